// Round 1
// 323.272 us; speedup vs baseline: 2.0843x; 2.0843x over previous
//
#include <hip/hip_runtime.h>

#define N_EMB 65536
#define DIM   512
#define K_C   256

// ws layout: cbg = frag-ordered bf16 hi/lo centroids (512 KiB) | cnorm = float[256] (1 KiB)

typedef __attribute__((ext_vector_type(4))) float        f32x4;
typedef __attribute__((ext_vector_type(8))) __bf16       bf16x8;
typedef __attribute__((ext_vector_type(8))) short        s16x8;
typedef __attribute__((ext_vector_type(4))) unsigned int u32x4;

// ---- MFMA wrapper. Primary: v8bf16 operands (LLVM gfx950 signature).
// SFINAE fallback bit-casts to v8i16 in case this ROCm's builtin wants shorts.
template <class T>
__device__ inline auto mfma_bf16_t(T a, T b, f32x4 c, int)
    -> decltype(__builtin_amdgcn_mfma_f32_16x16x32_bf16(a, b, c, 0, 0, 0)) {
  return __builtin_amdgcn_mfma_f32_16x16x32_bf16(a, b, c, 0, 0, 0);
}
template <class T>
__device__ inline f32x4 mfma_bf16_t(T a, T b, f32x4 c, long) {
  return __builtin_amdgcn_mfma_f32_16x16x32_bf16(
      __builtin_bit_cast(s16x8, a), __builtin_bit_cast(s16x8, b), c, 0, 0, 0);
}
__device__ inline f32x4 MFMA(bf16x8 a, bf16x8 b, f32x4 c) {
  return mfma_bf16_t(a, b, c, 0);
}

__device__ inline unsigned umin_(unsigned a, unsigned b) { return a < b ? a : b; }
__device__ inline unsigned umax_(unsigned a, unsigned b) { return a > b ? a : b; }

// 8 fp32 -> 8 (bf16 hi, bf16 lo) pairs, RNE both.  x ~= hi + lo, |resid| <= 2^-18|x|.
__device__ inline void cvt8(const float4 a, const float4 b, u32x4& hw, u32x4& lw) {
  float v[8] = {a.x, a.y, a.z, a.w, b.x, b.y, b.z, b.w};
  unsigned h[8], l[8];
#pragma unroll
  for (int i = 0; i < 8; ++i) {
    const unsigned u  = __float_as_uint(v[i]);
    const unsigned hb = (u + 0x7FFFu + ((u >> 16) & 1u)) >> 16;
    h[i] = hb;
    const float hf = __uint_as_float(hb << 16);
    const unsigned ul = __float_as_uint(v[i] - hf);
    l[i] = (ul + 0x7FFFu + ((ul >> 16) & 1u)) >> 16;
  }
  hw = (u32x4){h[0] | (h[1] << 16), h[2] | (h[3] << 16),
               h[4] | (h[5] << 16), h[6] | (h[7] << 16)};
  lw = (u32x4){l[0] | (l[1] << 16), l[2] | (l[3] << 16),
               l[4] | (l[5] << 16), l[6] | (l[7] << 16)};
}

// ---- prep: pack centroids to frag-ordered bf16 hi/lo.
// Layout: [chunk(16)][hi/lo(2)][ct(16)] blocks of 1 KiB; block = 64 lanes x 16B.
// Frag element: lane L holds C[ct*16 + (L&15)][chunk*32 + (L>>4)*8 + j], j=0..7.
__global__ void pack_centroids(const float* __restrict__ cent, unsigned* __restrict__ cbg) {
  const int k    = blockIdx.x;   // centroid
  const int lane = threadIdx.x;  // 0..63, dims lane*8..lane*8+7
  const float* src = cent + (size_t)k * DIM + lane * 8;
  u32x4 hw, lw;
  cvt8(*(const float4*)src, *(const float4*)(src + 4), hw, lw);
  const int chunk = lane >> 2;
  const int fl    = (lane & 3) * 16 + (k & 15);
  const int ct    = k >> 4;
  u32x4* base = (u32x4*)cbg;
  base[(((size_t)chunk * 2 + 0) * 16 + ct) * 64 + fl] = hw;
  base[(((size_t)chunk * 2 + 1) * 16 + ct) * 64 + fl] = lw;
}

__global__ void centroid_norms(const float* __restrict__ cent,
                               float* __restrict__ cnorm) {
  const int k = blockIdx.x;
  const int lane = threadIdx.x;  // 64 threads
  const float4* row = (const float4*)(cent + (size_t)k * DIM);
  float s = 0.f;
  for (int i = lane; i < DIM / 4; i += 64) {
    float4 v = row[i];
    s += v.x * v.x + v.y * v.y + v.z * v.z + v.w * v.w;
  }
#pragma unroll
  for (int off = 32; off > 0; off >>= 1) s += __shfl_down(s, off, 64);
  if (lane == 0) cnorm[k] = s;
}

// ---- main: 256 rows x 256 centroids per block, 512 threads (8 waves).
// dot(e,c) via 3-term split-bf16 MFMA: eh*ch + el*ch + eh*cl  (err sigma ~1e-4).
// Approx top-4/row in registers (packed score|col u32), exact fp32 rescore + gather.
__global__ __launch_bounds__(512, 2)
void neg_sampler_main(const float* __restrict__ emb,
                      const float* __restrict__ cent,
                      const unsigned* __restrict__ cbg,
                      const float* __restrict__ cnorm,
                      float* __restrict__ out) {
  extern __shared__ char lds[];
  char* const EH = lds;           // 16 KiB: E-hi frags, 16 row-tiles x 1 KiB
  char* const EL = lds + 16384;   // 16 KiB: E-lo frags
  char* const CB = lds + 32768;   // 32 KiB: C frags [hi 16K][lo 16K]

  const int tid  = threadIdx.x;
  const int lane = tid & 63;
  const int w    = tid >> 6;              // wave 0..7 -> row tiles 2w, 2w+1
  const int row0 = blockIdx.x * 256;

  f32x4 acc[2][16];
#pragma unroll
  for (int i = 0; i < 2; ++i)
#pragma unroll
    for (int j = 0; j < 16; ++j) acc[i][j] = (f32x4){0.f, 0.f, 0.f, 0.f};

  // E staging: thread handles row er, dim-groups eg0 and eg0+2 (8 dims each).
  const int er  = tid & 255;
  const int eg0 = tid >> 8;  // 0/1
  const float* const ebase = emb + (size_t)(row0 + er) * DIM;
  const int et = er >> 4, erow = er & 15;
  const int eoffA = et * 1024 + (eg0 * 16 + erow) * 16;
  const int eoffB = et * 1024 + ((eg0 + 2) * 16 + erow) * 16;

  float4 ev0, ev1, ev2, ev3;  // next-chunk E (2x8 dims)
  u32x4  cv0, cv1, cv2, cv3;  // next-chunk C frag data (linear copy)

  auto load_chunk = [&](int c) {
    const float* p0 = ebase + c * 32 + eg0 * 8;
    ev0 = *(const float4*)p0;
    ev1 = *(const float4*)(p0 + 4);
    ev2 = *(const float4*)(p0 + 16);
    ev3 = *(const float4*)(p0 + 20);
    const u32x4* cs = (const u32x4*)cbg + (size_t)c * 2048 + tid;
    cv0 = cs[0]; cv1 = cs[512]; cv2 = cs[1024]; cv3 = cs[1536];
  };
  auto store_chunk = [&]() {
    u32x4 hw, lw;
    cvt8(ev0, ev1, hw, lw);
    *(u32x4*)(EH + eoffA) = hw; *(u32x4*)(EL + eoffA) = lw;
    cvt8(ev2, ev3, hw, lw);
    *(u32x4*)(EH + eoffB) = hw; *(u32x4*)(EL + eoffB) = lw;
    u32x4* cd = (u32x4*)CB + tid;
    cd[0] = cv0; cd[512] = cv1; cd[1024] = cv2; cd[1536] = cv3;
  };

  load_chunk(0);
  for (int c = 0; c < 16; ++c) {
    if (c) __syncthreads();          // end of compute(c-1); prefetched VMEM is ~done
    store_chunk();                   // convert + ds_write (auto-waits own loads)
    if (c < 15) load_chunk(c + 1);   // prefetch stays in flight across raw barrier
    asm volatile("s_waitcnt lgkmcnt(0)" ::: "memory");  // my LDS writes done
    __builtin_amdgcn_sched_barrier(0);
    __builtin_amdgcn_s_barrier();    // raw: no vmcnt(0) drain -> prefetch survives
    asm volatile("" ::: "memory");

    const char* ehp = EH + (2 * w) * 1024 + lane * 16;
    const char* elp = EL + (2 * w) * 1024 + lane * 16;
    const bf16x8 eh0 = *(const bf16x8*)ehp;
    const bf16x8 eh1 = *(const bf16x8*)(ehp + 1024);
    const bf16x8 el0 = *(const bf16x8*)elp;
    const bf16x8 el1 = *(const bf16x8*)(elp + 1024);
    const char* cbp = CB + lane * 16;
#pragma unroll
    for (int ct = 0; ct < 16; ++ct) {
      const bf16x8 ch = *(const bf16x8*)(cbp + ct * 1024);
      const bf16x8 cl = *(const bf16x8*)(cbp + 16384 + ct * 1024);
      acc[0][ct] = MFMA(eh0, ch, acc[0][ct]);
      acc[1][ct] = MFMA(eh1, ch, acc[1][ct]);
      acc[0][ct] = MFMA(el0, ch, acc[0][ct]);
      acc[1][ct] = MFMA(el1, ch, acc[1][ct]);
      acc[0][ct] = MFMA(eh0, cl, acc[0][ct]);
      acc[1][ct] = MFMA(eh1, cl, acc[1][ct]);
    }
  }
  __syncthreads();

  // ---- approx top-4 per row. D tile mapping: row=(lane>>4)*4+reg, col=lane&15.
  unsigned* top4 = (unsigned*)lds;  // [256][4], reuses EH region
  const int lgrp = lane >> 4, lcol = lane & 15;
  float cnv[16];
#pragma unroll
  for (int ct = 0; ct < 16; ++ct) cnv[ct] = cnorm[ct * 16 + lcol];

#pragma unroll
  for (int rt = 0; rt < 2; ++rt) {
#pragma unroll
    for (int rg = 0; rg < 4; ++rg) {
      unsigned b0 = 0xFFFFFFFFu, b1 = b0, b2 = b0, b3 = b0;
      auto ins = [&](unsigned u) {
        b3 = umin_(b3, umax_(b2, u));
        b2 = umin_(b2, umax_(b1, u));
        b1 = umin_(b1, umax_(b0, u));
        b0 = umin_(b0, u);
      };
#pragma unroll
      for (int ct = 0; ct < 16; ++ct) {
        const float s = fmaf(-2.f, acc[rt][ct][rg], cnv[ct]);  // ||e||^2 drops
        ins((__float_as_uint(s) & 0xFFFFFF00u) | (unsigned)(ct * 16 + lcol));
      }
#pragma unroll
      for (int off = 1; off < 16; off <<= 1) {  // merge the 16 cols-lanes of a group
        const unsigned o0 = __shfl_xor(b0, off, 64);
        const unsigned o1 = __shfl_xor(b1, off, 64);
        const unsigned o2 = __shfl_xor(b2, off, 64);
        const unsigned o3 = __shfl_xor(b3, off, 64);
        ins(o0); ins(o1); ins(o2); ins(o3);
      }
      if (lcol == 0) {
        const int row = w * 32 + rt * 16 + lgrp * 4 + rg;
        *(u32x4*)(top4 + row * 4) = (u32x4){b0, b1, b2, b3};
      }
    }
  }
  __syncthreads();

  // ---- exact fp32 rescore of 4 candidates, pick exact 2nd-min, gather.
  for (int rr = 0; rr < 32; ++rr) {
    const int row  = w * 32 + rr;
    const int grow = row0 + row;
    const float* ep = emb + (size_t)grow * DIM + lane * 8;
    const float4 e0 = *(const float4*)ep;
    const float4 e1 = *(const float4*)(ep + 4);
    int cand[4];
    float sc[4];
#pragma unroll
    for (int j = 0; j < 4; ++j) cand[j] = (int)(top4[row * 4 + j] & 0xFFu);
#pragma unroll
    for (int j = 0; j < 4; ++j) {
      const float* cp = cent + (size_t)cand[j] * DIM + lane * 8;
      const float4 c0 = *(const float4*)cp;
      const float4 c1 = *(const float4*)(cp + 4);
      float d = e0.x * c0.x;
      d = fmaf(e0.y, c0.y, d); d = fmaf(e0.z, c0.z, d); d = fmaf(e0.w, c0.w, d);
      d = fmaf(e1.x, c1.x, d); d = fmaf(e1.y, c1.y, d);
      d = fmaf(e1.z, c1.z, d); d = fmaf(e1.w, c1.w, d);
#pragma unroll
      for (int off = 1; off < 64; off <<= 1) d += __shfl_xor(d, off, 64);
      sc[j] = fmaf(-2.f, d, cnorm[cand[j]]);
    }
    float v1 = 3.4e38f, v2 = 3.4e38f;
    int i1 = K_C, i2 = K_C;
#pragma unroll
    for (int j = 0; j < 4; ++j) {  // stable smaller-index tiebreak (matches top_k)
      const float s = sc[j];
      const int ci = cand[j];
      if (s < v1 || (s == v1 && ci < i1)) { v2 = v1; i2 = i1; v1 = s; i1 = ci; }
      else if (s < v2 || (s == v2 && ci < i2)) { v2 = s; i2 = ci; }
    }
    const float* sp = cent + (size_t)i2 * DIM + lane * 8;
    const float4 o0 = *(const float4*)sp;
    const float4 o1 = *(const float4*)(sp + 4);
    float* op = out + (size_t)grow * DIM + lane * 8;
    *(float4*)op       = o0;
    *(float4*)(op + 4) = o1;
  }
}

extern "C" void kernel_launch(void* const* d_in, const int* in_sizes, int n_in,
                              void* d_out, int out_size, void* d_ws, size_t ws_size,
                              hipStream_t stream) {
  const float* emb  = (const float*)d_in[0];
  const float* cent = (const float*)d_in[1];
  // d_in[2] = batch_id, unused.
  unsigned* cbg = (unsigned*)d_ws;                     // 512 KiB frag-ordered C
  float* cnorm  = (float*)((char*)d_ws + 512 * 1024);  // 1 KiB

  pack_centroids<<<K_C, 64, 0, stream>>>(cent, cbg);
  centroid_norms<<<K_C, 64, 0, stream>>>(cent, cnorm);
  neg_sampler_main<<<N_EMB / 256, 512, 65536, stream>>>(emb, cent, cbg, cnorm,
                                                        (float*)d_out);
}